// Round 7
// baseline (411.971 us; speedup 1.0000x reference)
//
#include <hip/hip_runtime.h>
#include <math.h>

// ---------------------------------------------------------------------------
// 2-layer GCN (PyG GCNConv semantics) on MI355X.
//   deg[c]  = #incoming edges + 1 (self loop); dinv = rsqrt(deg)
//   g       = bf16( dinv[n] * (X @ W) )     (MFMA GEMM + epilogue scale+pack)
//   out[c]  = dinv[c] * (g[c] + sum_{(r,c) in E} g[r]) + b   (CSR gather)
//   layer1: ReLU -> h1 (bf16); layer2: none, writes d_out (fp32).
// R10-R15 history: agg structure experiments (edge-parallel, coop idx, sort,
//   occupancy pin) all landed agg1 at ~60-61us across THREE different
//   codegens; agg2 (half the bytes) equal. Model: random 256B/128B row
//   gather is at a ~26G rows/s hardware floor. aggs are FROZEN at R15 form.
// R16: CSR build rebuilt as DIRECT global-atomic counting sort:
//   count (atomicAdd deg) -> scan -> init (off/cur/dinv) -> place
//   (pos=atomicAdd(cur[col]); src[pos]=row). Drops the pairs array
//   (12.8MB write + 19.2MB read) and one full edge pass vs the R9
//   bucketed sort. At E=1.6M, per-edge int atomics are ~us-scale; the
//   R8 "25G/s atomic cap" concerned much larger atomic volumes.
//   deg zeroing folded into wprep (no memset API during graph capture).
// ---------------------------------------------------------------------------

#define BS 256

typedef __attribute__((ext_vector_type(8))) short bf16x8;
typedef __attribute__((ext_vector_type(4))) float f32x4;
typedef __attribute__((ext_vector_type(4))) unsigned u32x4;

union FragU {
    bf16x8 v;
    unsigned u[4];
};

__device__ __forceinline__ unsigned pack_bf16x2(float a, float b) {
    unsigned ua = __float_as_uint(a);
    unsigned ub = __float_as_uint(b);
    ua = (ua + 0x7fffu + ((ua >> 16) & 1u)) >> 16;   // RTE
    ub = (ub + 0x7fffu + ((ub >> 16) & 1u)) >> 16;
    return ua | (ub << 16);
}

__device__ __forceinline__ ushort bf16_rte(float a) {
    unsigned ua = __float_as_uint(a);
    return (ushort)((ua + 0x7fffu + ((ua >> 16) & 1u)) >> 16);
}

__device__ __forceinline__ float bf_lo(unsigned u) { return __uint_as_float(u << 16); }
__device__ __forceinline__ float bf_hi(unsigned u) { return __uint_as_float(u & 0xffff0000u); }

// W^T-bf16 prep + deg zeroing (first kernel, independent of everything else).
__global__ __launch_bounds__(BS) void wprep_zero_kernel(const float* __restrict__ W1,
                                                        const float* __restrict__ W2,
                                                        ushort* __restrict__ wt1,
                                                        ushort* __restrict__ wt2,
                                                        int* __restrict__ deg, int n) {
    int t = blockIdx.x * BS + threadIdx.x;
    int NT = gridDim.x * BS;
    for (int i = t; i < n; i += NT) deg[i] = 0;
    if (t < 128 * 128) {
        int nn = t >> 7, k = t & 127;
        wt1[t] = bf16_rte(W1[k * 128 + nn]);
    }
    if (t < 64 * 128) {
        int nn = t >> 7, k = t & 127;
        wt2[t] = bf16_rte(W2[k * 64 + nn]);
    }
}

// count: deg[col]++ for every edge (int4-vectorized edge reads).
__global__ __launch_bounds__(BS) void count_kernel(const int* __restrict__ col,
                                                   int* __restrict__ deg, int E) {
    int t = blockIdx.x * BS + threadIdx.x;
    int n4 = E >> 2;
    const int4* c4 = (const int4*)col;
    if (t < n4) {
        int4 c = c4[t];
        atomicAdd(&deg[c.x], 1);
        atomicAdd(&deg[c.y], 1);
        atomicAdd(&deg[c.z], 1);
        atomicAdd(&deg[c.w], 1);
    }
    int r = (n4 << 2) + t;
    if (r < E) atomicAdd(&deg[col[r]], 1);
}

// block-exclusive scan (block-local; boff completes it at use sites)
__global__ __launch_bounds__(BS) void scan_block_kernel(const int* __restrict__ in,
                                                        int* __restrict__ exc,
                                                        int* __restrict__ bsum, int N) {
    __shared__ int s[BS];
    int tid = threadIdx.x;
    int i = blockIdx.x * BS + tid;
    int v = (i < N) ? in[i] : 0;
    s[tid] = v;
    __syncthreads();
    for (int off = 1; off < BS; off <<= 1) {
        int t = (tid >= off) ? s[tid - off] : 0;
        __syncthreads();
        s[tid] += t;
        __syncthreads();
    }
    if (i < N) exc[i] = s[tid] - v;
    if (tid == BS - 1) bsum[blockIdx.x] = s[BS - 1];
}

__global__ __launch_bounds__(512) void scan_bsum_kernel(const int* __restrict__ bsum,
                                                        int* __restrict__ boff, int NB) {
    __shared__ int s[512];
    int tid = threadIdx.x;
    int v = (tid < NB) ? bsum[tid] : 0;
    s[tid] = v;
    __syncthreads();
    for (int off = 1; off < 512; off <<= 1) {
        int t = (tid >= off) ? s[tid - off] : 0;
        __syncthreads();
        s[tid] += t;
        __syncthreads();
    }
    if (tid < NB) boff[tid] = s[tid] - v;
}

// init: off/cur = global exclusive scan; dinv from deg.
__global__ __launch_bounds__(BS) void init_kernel(const int* __restrict__ exc,
                                                  const int* __restrict__ boff,
                                                  const int* __restrict__ deg,
                                                  int* __restrict__ off,
                                                  int* __restrict__ cur,
                                                  float* __restrict__ dinv, int n) {
    int i = blockIdx.x * BS + threadIdx.x;
    if (i < n) {
        int base = exc[i] + boff[i >> 8];
        off[i] = base;
        cur[i] = base;
        dinv[i] = rsqrtf((float)(deg[i] + 1));
    }
}

// place: src[atomicAdd(cur[col])] = row (int4-vectorized edge reads).
__global__ __launch_bounds__(BS) void place_kernel(const int* __restrict__ row,
                                                   const int* __restrict__ col,
                                                   int* __restrict__ cur,
                                                   int* __restrict__ src, int E) {
    int t = blockIdx.x * BS + threadIdx.x;
    int n4 = E >> 2;
    const int4* c4 = (const int4*)col;
    const int4* r4 = (const int4*)row;
    if (t < n4) {
        int4 c = c4[t];
        int4 r = r4[t];
        int p0 = atomicAdd(&cur[c.x], 1);
        int p1 = atomicAdd(&cur[c.y], 1);
        int p2 = atomicAdd(&cur[c.z], 1);
        int p3 = atomicAdd(&cur[c.w], 1);
        src[p0] = r.x;
        src[p1] = r.y;
        src[p2] = r.z;
        src[p3] = r.w;
    }
    int rr = (n4 << 2) + t;
    if (rr < E) {
        int p = atomicAdd(&cur[col[rr]], 1);
        src[p] = row[rr];
    }
}

// G[m][ch] (bf16 packed) = bf16( dinv[m] * (A[m][128] @ W[128][NCH]) )
// MFMA 16x16x32, transposed: A-op = W^T (LDS, padded stride 136 shorts),
// B-op = A rows (global, fp32->bf16 in-reg if !IN_BF16).
template <int NCH, bool IN_BF16>
__global__ __launch_bounds__(BS) void gemm_mfma_kernel(const void* __restrict__ Ain,
                                                       const ushort* __restrict__ WT,
                                                       const float* __restrict__ dinv,
                                                       unsigned* __restrict__ G, int n) {
    constexpr int NT = NCH / 16;          // channel tiles
    constexpr int KP = 136;               // padded W^T row stride (shorts)
    __shared__ ushort wlds[NCH * KP];

    int tid = threadIdx.x;
    for (int c = tid; c < NCH * 16; c += BS) {
        int nr = c >> 4, q16 = c & 15;
        *(uint4*)(wlds + nr * KP + q16 * 8) = ((const uint4*)WT)[c];
    }
    __syncthreads();

    int lane = tid & 63, wv = tid >> 6;
    int ml = lane & 15, quad = lane >> 4;
    int m = blockIdx.x * 64 + wv * 16 + ml;

    FragU b[4];
    if (m < n) {
        if (IN_BF16) {
#pragma unroll
            for (int ks = 0; ks < 4; ++ks) {
                uint4 t = ((const uint4*)Ain)[(size_t)m * 16 + ks * 4 + quad];
                b[ks].u[0] = t.x; b[ks].u[1] = t.y; b[ks].u[2] = t.z; b[ks].u[3] = t.w;
            }
        } else {
            const float4* A = (const float4*)Ain + (size_t)m * 32;
#pragma unroll
            for (int ks = 0; ks < 4; ++ks) {
                float4 p0 = A[ks * 8 + quad * 2];
                float4 p1 = A[ks * 8 + quad * 2 + 1];
                b[ks].u[0] = pack_bf16x2(p0.x, p0.y);
                b[ks].u[1] = pack_bf16x2(p0.z, p0.w);
                b[ks].u[2] = pack_bf16x2(p1.x, p1.y);
                b[ks].u[3] = pack_bf16x2(p1.z, p1.w);
            }
        }
    } else {
#pragma unroll
        for (int ks = 0; ks < 4; ++ks) {
            b[ks].u[0] = 0; b[ks].u[1] = 0; b[ks].u[2] = 0; b[ks].u[3] = 0;
        }
    }

    f32x4 acc[NT];
#pragma unroll
    for (int nt = 0; nt < NT; ++nt) {
        acc[nt][0] = 0.f; acc[nt][1] = 0.f; acc[nt][2] = 0.f; acc[nt][3] = 0.f;
    }

#pragma unroll
    for (int nt = 0; nt < NT; ++nt) {
#pragma unroll
        for (int ks = 0; ks < 4; ++ks) {
            bf16x8 a = *(const bf16x8*)(wlds + (nt * 16 + ml) * KP + ks * 32 + quad * 8);
            acc[nt] = __builtin_amdgcn_mfma_f32_16x16x32_bf16(a, b[ks].v, acc[nt], 0, 0, 0);
        }
    }

    if (m < n) {
        float dv = dinv[m];
        unsigned* grow = G + (size_t)m * (NCH / 2);
#pragma unroll
        for (int nt = 0; nt < NT; ++nt) {
            uint2 o;
            o.x = pack_bf16x2(acc[nt][0] * dv, acc[nt][1] * dv);
            o.y = pack_bf16x2(acc[nt][2] * dv, acc[nt][3] * dv);
            *(uint2*)(grow + nt * 8 + quad * 2) = o;
        }
    }
}

// out[node][c] = act( dinv[node] * (G[node][c] + sum_{s in CSR(node)} G[s][c]) + b[c] )
// G bf16-packed; each lane covers 8 channels (one uint4). FROZEN R15 form:
// Gp=16: coop idx load + two 8-deep bursts + 8/4/2/1 ladder.
// Gp=8: 16-edge chunks via two idx regs + cross-iteration prefetch.
template <int C, bool RELU, bool OUT_BF16>
__global__ __launch_bounds__(BS) void agg_kernel(const unsigned* __restrict__ G,
                                                 const int* __restrict__ edge_off,
                                                 const int* __restrict__ cnt,
                                                 const int* __restrict__ src,
                                                 const float* __restrict__ dinv,
                                                 const float* __restrict__ bias,
                                                 void* __restrict__ out, int n) {
    constexpr int Gp = C / 8;          // uint4 lanes per node (16 or 8)
    constexpr int NPB = BS / Gp;       // nodes per block
    int lane = threadIdx.x & (Gp - 1);
    int li = threadIdx.x / Gp;
    int node = blockIdx.x * NPB + li;
    if (node >= n) return;

    const uint4* G4 = (const uint4*)G;
    float acc[8];
    {
        uint4 sv = G4[(size_t)node * Gp + lane];   // self-loop term
        acc[0] = bf_lo(sv.x); acc[1] = bf_hi(sv.x);
        acc[2] = bf_lo(sv.y); acc[3] = bf_hi(sv.y);
        acc[4] = bf_lo(sv.z); acc[5] = bf_hi(sv.z);
        acc[6] = bf_lo(sv.w); acc[7] = bf_hi(sv.w);
    }
    const int* sp = src + edge_off[node];
    int deg = cnt[node];

#define ACCUM(v)                                                               \
    acc[0] += bf_lo(v.x); acc[1] += bf_hi(v.x);                                \
    acc[2] += bf_lo(v.y); acc[3] += bf_hi(v.y);                                \
    acc[4] += bf_lo(v.z); acc[5] += bf_hi(v.z);                                \
    acc[6] += bf_lo(v.w); acc[7] += bf_hi(v.w);

    if constexpr (Gp == 16) {
        // ---- layer-1 path ----
        int i = 0;
        for (; i + Gp <= deg; i += Gp) {
            int myi = __builtin_nontemporal_load(sp + i + lane);
#pragma unroll
            for (int h = 0; h < Gp / 8; ++h) {
                uint4 v[8];
#pragma unroll
                for (int u = 0; u < 8; ++u) {
                    int s = __shfl(myi, h * 8 + u, Gp);
                    v[u] = G4[(size_t)s * Gp + lane];
                }
#pragma unroll
                for (int u = 0; u < 8; ++u) { ACCUM(v[u]) }
            }
        }
        int rem = deg - i;
        if (rem > 0) {
            int myi = (lane < rem) ? __builtin_nontemporal_load(sp + i + lane) : 0;
            int j = 0;
            if (rem >= 8) {
                uint4 v[8];
#pragma unroll
                for (int u = 0; u < 8; ++u) {
                    int s = __shfl(myi, u, Gp);
                    v[u] = G4[(size_t)s * Gp + lane];
                }
#pragma unroll
                for (int u = 0; u < 8; ++u) { ACCUM(v[u]) }
                j = 8;
            }
            if (rem - j >= 4) {
                uint4 v[4];
#pragma unroll
                for (int u = 0; u < 4; ++u) {
                    int s = __shfl(myi, j + u, Gp);
                    v[u] = G4[(size_t)s * Gp + lane];
                }
#pragma unroll
                for (int u = 0; u < 4; ++u) { ACCUM(v[u]) }
                j += 4;
            }
            if (rem - j >= 2) {
                int s0 = __shfl(myi, j, Gp);
                int s1 = __shfl(myi, j + 1, Gp);
                uint4 v0 = G4[(size_t)s0 * Gp + lane];
                uint4 v1 = G4[(size_t)s1 * Gp + lane];
                ACCUM(v0) ACCUM(v1)
                j += 2;
            }
            if (rem - j >= 1) {
                int s0 = __shfl(myi, j, Gp);
                uint4 v0 = G4[(size_t)s0 * Gp + lane];
                ACCUM(v0)
            }
        }
    } else {
        // ---- layer-2 path: 16-edge chunks, two idx regs, prefetch ahead ----
        int myi0 = __builtin_nontemporal_load(sp + lane);
        int myi1 = __builtin_nontemporal_load(sp + 8 + lane);
        int i = 0;
        for (; i + 16 <= deg; i += 16) {
            int nx0 = __builtin_nontemporal_load(sp + i + 16 + lane);
            int nx1 = __builtin_nontemporal_load(sp + i + 24 + lane);
            uint4 v[8];
#pragma unroll
            for (int u = 0; u < 8; ++u) {
                int s = __shfl(myi0, u, Gp);
                v[u] = G4[(size_t)s * Gp + lane];
            }
#pragma unroll
            for (int u = 0; u < 8; ++u) { ACCUM(v[u]) }
#pragma unroll
            for (int u = 0; u < 8; ++u) {
                int s = __shfl(myi1, u, Gp);
                v[u] = G4[(size_t)s * Gp + lane];
            }
#pragma unroll
            for (int u = 0; u < 8; ++u) { ACCUM(v[u]) }
            myi0 = nx0;
            myi1 = nx1;
        }
        int rem = deg - i;            // 0..15
        if (rem >= 8) {
            uint4 v[8];
#pragma unroll
            for (int u = 0; u < 8; ++u) {
                int s = __shfl(myi0, u, Gp);
                v[u] = G4[(size_t)s * Gp + lane];
            }
#pragma unroll
            for (int u = 0; u < 8; ++u) { ACCUM(v[u]) }
        }
        int rest = (rem >= 8) ? myi1 : myi0;
        int jb = 0;
        int r2 = rem & 7;
        if (r2 >= 4) {
            uint4 v[4];
#pragma unroll
            for (int u = 0; u < 4; ++u) {
                int s = __shfl(rest, jb + u, Gp);
                v[u] = G4[(size_t)s * Gp + lane];
            }
#pragma unroll
            for (int u = 0; u < 4; ++u) { ACCUM(v[u]) }
            jb += 4;
        }
        if (r2 & 2) {
            int s0 = __shfl(rest, jb, Gp);
            int s1 = __shfl(rest, jb + 1, Gp);
            uint4 v0 = G4[(size_t)s0 * Gp + lane];
            uint4 v1 = G4[(size_t)s1 * Gp + lane];
            ACCUM(v0) ACCUM(v1)
            jb += 2;
        }
        if (r2 & 1) {
            int s0 = __shfl(rest, jb, Gp);
            uint4 v0 = G4[(size_t)s0 * Gp + lane];
            ACCUM(v0)
        }
    }
#undef ACCUM

    float dv = dinv[node];
    const float4* b4 = (const float4*)bias;
    float4 bl = b4[2 * lane + 0], bh = b4[2 * lane + 1];
    float o0x = acc[0] * dv + bl.x, o0y = acc[1] * dv + bl.y;
    float o0z = acc[2] * dv + bl.z, o0w = acc[3] * dv + bl.w;
    float o1x = acc[4] * dv + bh.x, o1y = acc[5] * dv + bh.y;
    float o1z = acc[6] * dv + bh.z, o1w = acc[7] * dv + bh.w;
    if (RELU) {
        o0x = fmaxf(o0x, 0.f); o0y = fmaxf(o0y, 0.f);
        o0z = fmaxf(o0z, 0.f); o0w = fmaxf(o0w, 0.f);
        o1x = fmaxf(o1x, 0.f); o1y = fmaxf(o1y, 0.f);
        o1z = fmaxf(o1z, 0.f); o1w = fmaxf(o1w, 0.f);
    }
    if (OUT_BF16) {
        u32x4 ov;
        ov.x = pack_bf16x2(o0x, o0y);
        ov.y = pack_bf16x2(o0z, o0w);
        ov.z = pack_bf16x2(o1x, o1y);
        ov.w = pack_bf16x2(o1z, o1w);
        __builtin_nontemporal_store(ov, (u32x4*)out + (size_t)node * Gp + lane);
    } else {
        f32x4* orow = (f32x4*)((float*)out + (size_t)node * C);
        f32x4 o0; o0.x = o0x; o0.y = o0y; o0.z = o0z; o0.w = o0w;
        f32x4 o1; o1.x = o1x; o1.y = o1y; o1.z = o1z; o1.w = o1w;
        __builtin_nontemporal_store(o0, orow + 2 * lane + 0);
        __builtin_nontemporal_store(o1, orow + 2 * lane + 1);
    }
}

extern "C" void kernel_launch(void* const* d_in, const int* in_sizes, int n_in,
                              void* d_out, int out_size, void* d_ws, size_t ws_size,
                              hipStream_t stream) {
    const float* x  = (const float*)d_in[0];
    const int*   ei = (const int*)d_in[1];      // [2, E] int32
    const float* W1 = (const float*)d_in[2];
    const float* b1 = (const float*)d_in[3];
    const float* W2 = (const float*)d_in[4];
    const float* b2 = (const float*)d_in[5];

    const int IN_C = 128, HID_C = 128;
    int n = in_sizes[0] / IN_C;
    int E = in_sizes[1] / 2;
    const int* row = ei;
    const int* col = ei + E;

    int NBS = (n + BS - 1) / BS;                // scan blocks over nodes (<=512)

    char* w = (char*)d_ws;
    auto alloc = [&](size_t bytes) {
        void* p = (void*)w;
        w += (bytes + 255) & ~(size_t)255;
        return p;
    };
    int*      deg     = (int*)alloc((size_t)n * 4);
    int*      exc     = (int*)alloc((size_t)n * 4);
    int*      bsum    = (int*)alloc((size_t)NBS * 4);
    int*      boff    = (int*)alloc((size_t)NBS * 4);
    int*      cur     = (int*)alloc((size_t)n * 4);
    int*      off     = (int*)alloc((size_t)n * 4);
    float*    dinv    = (float*)alloc((size_t)n * 4);
    int*      src     = (int*)alloc((size_t)E * 4);   // followed by wt1: OOB
    ushort*   wt1     = (ushort*)alloc(128 * 128 * 2); // prefetch slack is safe
    ushort*   wt2     = (ushort*)alloc(64 * 128 * 2);
    unsigned* g       = (unsigned*)alloc((size_t)n * HID_C * 2);  // bf16-packed
    unsigned* h1b     = (unsigned*)alloc((size_t)n * HID_C * 2);  // bf16-packed h1

    int n4 = E >> 2;
    int gridE = (n4 + BS - 1) / BS;

    // W^T-bf16 prep + deg zeroing
    wprep_zero_kernel<<<64, BS, 0, stream>>>(W1, W2, wt1, wt2, deg, n);

    // CSR build: direct global-atomic counting sort
    count_kernel<<<gridE, BS, 0, stream>>>(col, deg, E);
    scan_block_kernel<<<NBS, BS, 0, stream>>>(deg, exc, bsum, n);
    scan_bsum_kernel<<<1, 512, 0, stream>>>(bsum, boff, NBS);
    init_kernel<<<NBS, BS, 0, stream>>>(exc, boff, deg, off, cur, dinv, n);
    place_kernel<<<gridE, BS, 0, stream>>>(row, col, cur, src, E);

    int gridM = (n + 63) / 64;

    // layer 1: g = bf16(dinv * (x @ W1)); h1b = bf16(relu(dinv*(self+gather)+b1))
    gemm_mfma_kernel<128, false><<<gridM, BS, 0, stream>>>(x, wt1, dinv, g, n);
    agg_kernel<128, true, true><<<(n + 15) / 16, BS, 0, stream>>>(g, off, deg, src,
                                                                  dinv, b1, h1b, n);

    // layer 2: g2 = bf16(dinv * (h1 @ W2)); out = dinv*(self+gather) + b2 (fp32)
    gemm_mfma_kernel<64, true><<<gridM, BS, 0, stream>>>(h1b, wt2, dinv, g, n);
    agg_kernel<64, false, false><<<(n + 31) / 32, BS, 0, stream>>>(g, off, deg, src,
                                                                   dinv, b2, d_out, n);
}